// Round 7
// baseline (809.315 us; speedup 1.0000x reference)
//
#include <hip/hip_runtime.h>

#define HBV_B  1024
#define HBV_NZ 1e-5f
#define BUFSZ  (15 * 64)       // one 15-step chunk buffer (64 lanes)

// ---------------------------------------------------------------------------
// Dual-chain 3-stage pipeline. Calibration (R4-R6): dependent VALU ~6 cyc,
// hw v_log/v_exp dependent latency ~55-60 cyc, chain latency K ~250 cyc/step,
// and single-chain time/step = issue + K (no overlap). Fix: each soil thread
// carries TWO independent cells (b, b+512), source-interleaved, so chain A's
// trans-latency gaps absorb chain B's issue -> time/step = max(issue, K).
//   wave 0: SM/SLZ/SUZ core + Q export for both sets (issue ~155 < K).
//   wave 1: snow recurrence (one chunk ahead) + FIR routing + DPP mean +
//           store (one chunk behind) for both sets.
// Phase p: wave0 soil chunk p-1 (parity (p-1)&1); wave1 snow chunk p
// (parity p&1) + route chunk p-2 (parity p&1). 135 barriers each.
// ---------------------------------------------------------------------------

struct F3 { float x, y, z; };

#define DPP_ADD_ROR(x, ctrl) do {                                              \
    int _r = __builtin_amdgcn_update_dpp(0, __float_as_int(x),                 \
                                         (ctrl), 0xF, 0xF, true);              \
    (x) += __int_as_float(_r);                                                 \
} while (0)

// Two soil steps (sets 0/1), manually interleaved line-by-line.
#define SOIL2(s) do {                                                          \
    float rt0 = rr[0][s],  rt1 = rr[1][s];                                     \
    float lp0 = lpv[0][s], lp1 = lpv[1][s];                                    \
    float lSMa = __builtin_amdgcn_logf(SM0);                                   \
    float lSMb = __builtin_amdgcn_logf(SM1);                                   \
    float cpet0 = lp0 + nBEloglpfc[0], cpet1 = lp1 + nBEloglpfc[1];            \
    float CSLZ0 = parC[0] * SLZ0,      CSLZ1 = parC[1] * SLZ1;                 \
    float c1a = __builtin_fmaf(-CSLZ0, invFC[0], 1.0f);                        \
    float c1b = __builtin_fmaf(-CSLZ1, invFC[1], 1.0f);                        \
    float SMrt0 = SM0 + rt0, SMrt1 = SM1 + rt1;                                \
    float esw0 = fminf(__builtin_fmaf(parBETA[0], lSMa, nBlogFC[0]), 0.0f);    \
    float esw1 = fminf(__builtin_fmaf(parBETA[1], lSMb, nBlogFC[1]), 0.0f);    \
    float sw0 = __builtin_amdgcn_exp2f(esw0);                                  \
    float sw1 = __builtin_amdgcn_exp2f(esw1);                                  \
    float SM1a = __builtin_fmaf(-rt0, sw0, SMrt0);                             \
    float SM1b = __builtin_fmaf(-rt1, sw1, SMrt1);                             \
    float SM2a = fminf(SM1a, parFC[0]), SM2b = fminf(SM1b, parFC[1]);          \
    float SM3a = __builtin_fmaf(SM2a, c1a, CSLZ0);                             \
    float SM3b = __builtin_fmaf(SM2b, c1b, CSLZ1);                             \
    float lS3a = __builtin_amdgcn_logf(SM3a);                                  \
    float lS3b = __builtin_amdgcn_logf(SM3b);                                  \
    float eef0 = fminf(__builtin_fmaf(parBETAET[0], lS3a, cpet0), lp0);        \
    float eef1 = fminf(__builtin_fmaf(parBETAET[1], lS3b, cpet1), lp1);        \
    float pe0 = __builtin_amdgcn_exp2f(eef0);                                  \
    float pe1 = __builtin_amdgcn_exp2f(eef1);                                  \
    SM0 = fmaxf(SM3a - pe0, HBV_NZ);                                           \
    SM1 = fmaxf(SM3b - pe1, HBV_NZ);                                           \
    /* off-chain Q path (folded, exact) */                                     \
    float U0 = __builtin_fmaf(rt0, sw0, SM1a - SM2a);  /* recharge+excess */   \
    float U1 = __builtin_fmaf(rt1, sw1, SM1b - SM2b);                          \
    float S0 = SUZ0 + U0, S1 = SUZ1 + U1;                                      \
    float P0 = fminf(S0, parPERC[0]), P1 = fminf(S1, parPERC[1]);              \
    float A0 = S0 - P0, A1 = S1 - P1;                                          \
    float B0 = fminf(A0, __builtin_fmaf(K0c[0], A0, K0UZL[0]));                \
    float B1 = fminf(A1, __builtin_fmaf(K0c[1], A1, K0UZL[1]));                \
    SUZ0 = K1c[0] * B0;  SUZ1 = K1c[1] * B1;                                   \
    float L0 = SLZ0 - (SM3a - SM2a) + P0;                                      \
    float L1 = SLZ1 - (SM3b - SM2b) + P1;                                      \
    SLZ0 = K2c[0] * L0;  SLZ1 = K2c[1] * L1;                                   \
    qd0[(s) * 64] = __builtin_fmaf(parK2[0], L0, A0 - SUZ0);                   \
    qd1[(s) * 64] = __builtin_fmaf(parK2[1], L1, A1 - SUZ1);                   \
} while (0)

__global__ __launch_bounds__(128, 1)
void hbv_dual_kernel(const float* __restrict__ x_phy,   // (2000, 1024, 3)
                     const float* __restrict__ ps,      // (1024, 288)
                     float* __restrict__ out)           // (2000, 1024)
{
    const int lane = (int)threadIdx.x & 63;
    const int wv   = (int)threadIdx.x >> 6;
    const int bA   = blockIdx.x * 4 + (lane >> 4);   // set0 cell; set1 = +512
    const int m    = lane & 15;

    __shared__ float qS [2][2 * BUFSZ];   // Qsim       (soil -> route)
    __shared__ float rtS[2][2 * BUFSZ];   // rain+tosoil (snow -> soil)
    __shared__ float lpS[2][2 * BUFSZ];   // log2(PET)   (snow -> soil)

    if (wv == 0) {
        // ---------------- soil: the critical wave, 2 chains/lane -----------
        float parBETA[2], parFC[2], invFC[2], parPERC[2], parBETAET[2];
        float parC[2], K0c[2], K0UZL[2], K1c[2], K2c[2], parK2[2];
        float nBlogFC[2], nBEloglpfc[2];
#pragma unroll
        for (int ci = 0; ci < 2; ++ci) {
            const float* pb = ps + (size_t)(bA + ci * 512) * 288;
            parBETA[ci]   = 1.0f   + pb[ 0*16 + m] * 5.0f;
            parFC[ci]     = 50.0f  + pb[ 1*16 + m] * 950.0f;
            float k0      = 0.05f  + pb[ 2*16 + m] * 0.85f;
            float k1      = 0.01f  + pb[ 3*16 + m] * 0.49f;
            float k2      = 0.001f + pb[ 4*16 + m] * 0.199f;
            float lpar    = 0.2f   + pb[ 5*16 + m] * 0.8f;
            parPERC[ci]   =          pb[ 6*16 + m] * 10.0f;
            float uzl     =          pb[ 7*16 + m] * 100.0f;
            parBETAET[ci] = 0.3f   + pb[12*16 + m] * 4.7f;
            parC[ci]      =          pb[13*16 + m];
            invFC[ci] = 1.0f / parFC[ci];
            K0c[ci] = 1.0f - k0;  K0UZL[ci] = k0 * uzl;
            K1c[ci] = 1.0f - k1;  K2c[ci] = 1.0f - k2;  parK2[ci] = k2;
            nBlogFC[ci]    = -parBETA[ci]   * __builtin_amdgcn_logf(parFC[ci]);
            nBEloglpfc[ci] = -parBETAET[ci] * __builtin_amdgcn_logf(lpar * parFC[ci]);
        }
        float SM0 = HBV_NZ, SM1 = HBV_NZ, SUZ0 = HBV_NZ, SUZ1 = HBV_NZ,
              SLZ0 = HBV_NZ, SLZ1 = HBV_NZ;

        __syncthreads();                                   // pair w/ p=0
#pragma unroll 1
        for (int c = 0; c < 133; ++c) {                    // full chunks
            const int po = (c & 1) * BUFSZ + lane;
            float rr[2][15], lpv[2][15];
#pragma unroll
            for (int ci = 0; ci < 2; ++ci)
#pragma unroll
                for (int k = 0; k < 15; ++k) {
                    rr[ci][k]  = rtS[ci][po + k * 64];
                    lpv[ci][k] = lpS[ci][po + k * 64];
                }
            float* const qd0 = &qS[0][po];
            float* const qd1 = &qS[1][po];
#pragma unroll
            for (int s = 0; s < 15; ++s) SOIL2(s);
            __syncthreads();
        }
        {   // tail chunk 133 (5 steps), parity 1
            const int po = BUFSZ + lane;
            float rr[2][15], lpv[2][15];
#pragma unroll
            for (int ci = 0; ci < 2; ++ci)
#pragma unroll
                for (int k = 0; k < 5; ++k) {
                    rr[ci][k]  = rtS[ci][po + k * 64];
                    lpv[ci][k] = lpS[ci][po + k * 64];
                }
            float* const qd0 = &qS[0][po];
            float* const qd1 = &qS[1][po];
#pragma unroll
            for (int s = 0; s < 5; ++s) SOIL2(s);
            __syncthreads();
        }
        // 135 barriers.
    } else {
        // ------------- snow (ahead) + routing (behind), 2 sets -------------
        float parTT[2], parCFMAX[2], negCT[2], CFRC[2], CFRCTT[2], parCWH[2];
        float w[2][15];
#pragma unroll
        for (int ci = 0; ci < 2; ++ci) {
            const float* pb = ps + (size_t)(bA + ci * 512) * 288;
            parTT[ci]    = -2.5f + pb[ 8*16 + m] * 5.0f;
            parCFMAX[ci] = 0.5f  + pb[ 9*16 + m] * 9.5f;
            float cfr    =         pb[10*16 + m] * 0.1f;
            parCWH[ci]   =         pb[11*16 + m] * 0.2f;
            CFRC[ci]   = cfr * parCFMAX[ci];
            negCT[ci]  = -parCFMAX[ci] * parTT[ci];
            CFRCTT[ci] =  CFRC[ci] * parTT[ci];
            float rout_a = pb[256 + m]      * 2.9f;
            float rout_b = pb[256 + 16 + m] * 6.5f;
            // w[k] ∝ t_k^(a-1) exp(-t_k/theta); Gamma/theta^a cancels under
            // normalization; pre-scaled by 1/16 for the mean over m.
            float aa    = fmaxf(rout_a, 0.0f) + 0.1f;
            float theta = fmaxf(rout_b, 0.0f) + 0.5f;
            float am1   = aa - 1.0f;
            float nit   = -1.4426950408889634f / theta;
            float wsum = 0.0f;
#pragma unroll
            for (int k = 0; k < 15; ++k) {
                float tk = (float)k + 0.5f;
                float e  = am1 * __builtin_amdgcn_logf(tk) + nit * tk;
                w[ci][k] = __builtin_amdgcn_exp2f(e);
                wsum += w[ci][k];
            }
            float wscale = 1.0f / (16.0f * wsum);
#pragma unroll
            for (int k = 0; k < 15; ++k) w[ci][k] *= wscale;
        }
        float q[2][15];
#pragma unroll
        for (int ci = 0; ci < 2; ++ci)
#pragma unroll
            for (int k = 0; k < 15; ++k) q[ci][k] = 0.0f;
        float SNW[2] = {HBV_NZ, HBV_NZ}, MLT[2] = {HBV_NZ, HBV_NZ};

        const F3* __restrict__ xb3_0 = (const F3*)x_phy + bA;
        const F3* __restrict__ xb3_1 = (const F3*)x_phy + bA + 512;

#define SNOWLOAD(cidx, n) do {                                                 \
    _Pragma("unroll")                                                          \
    for (int k_ = 0; k_ < (n); ++k_) {                                         \
        F3 fa = xb3_0[(size_t)((cidx) * 15 + k_) * HBV_B];                     \
        F3 fb = xb3_1[(size_t)((cidx) * 15 + k_) * HBV_B];                     \
        Pf[0][k_] = fa.x; Tf[0][k_] = fa.y; Ef[0][k_] = fa.z;                  \
        Pf[1][k_] = fb.x; Tf[1][k_] = fb.y; Ef[1][k_] = fb.z;                  \
    }                                                                          \
} while (0)

#define SNOW_RUN(n, po) do {                                                   \
    _Pragma("unroll")                                                          \
    for (int s_ = 0; s_ < (n); ++s_) {                                         \
        _Pragma("unroll")                                                      \
        for (int ci = 0; ci < 2; ++ci) {                                       \
            float Pm = Pf[ci][s_], Tc = Tf[ci][s_], PETm = Ef[ci][s_];         \
            float rain = (Tc >= parTT[ci]) ? Pm : 0.0f;                        \
            SNW[ci] += Pm - rain;                                              \
            float melt = fminf(fmaxf(                                          \
                __builtin_fmaf(parCFMAX[ci], Tc, negCT[ci]), 0.0f), SNW[ci]);  \
            MLT[ci] += melt; SNW[ci] -= melt;                                  \
            float rfz = fminf(fmaxf(                                           \
                __builtin_fmaf(-CFRC[ci], Tc, CFRCTT[ci]), 0.0f), MLT[ci]);    \
            SNW[ci] += rfz; MLT[ci] -= rfz;                                    \
            float tosoil = fmaxf(                                              \
                __builtin_fmaf(-parCWH[ci], SNW[ci], MLT[ci]), 0.0f);          \
            MLT[ci] -= tosoil;                                                 \
            rtS[ci][(po) + s_ * 64] = rain + tosoil;                           \
            lpS[ci][(po) + s_ * 64] = __builtin_amdgcn_logf(PETm);             \
        }                                                                      \
    }                                                                          \
} while (0)

#define ROUTE_RUN(n, po, tb) do {                                              \
    float qq[2][15];                                                           \
    _Pragma("unroll")                                                          \
    for (int ci = 0; ci < 2; ++ci)                                             \
        _Pragma("unroll")                                                      \
        for (int k_ = 0; k_ < (n); ++k_) qq[ci][k_] = qS[ci][(po) + k_ * 64];  \
    _Pragma("unroll")                                                          \
    for (int s_ = 0; s_ < (n); ++s_) {                                         \
        _Pragma("unroll")                                                      \
        for (int ci = 0; ci < 2; ++ci) {                                       \
            q[ci][s_] = qq[ci][s_];                                            \
            float qr = 0.0f;                                                   \
            _Pragma("unroll")                                                  \
            for (int k_ = 0; k_ < 15; ++k_)                                    \
                qr += w[ci][k_] * q[ci][(s_ - k_ + 15) % 15];                  \
            DPP_ADD_ROR(qr, 0x128);                                            \
            DPP_ADD_ROR(qr, 0x124);                                            \
            DPP_ADD_ROR(qr, 0x122);                                            \
            DPP_ADD_ROR(qr, 0x121);                                            \
            if (m == 0)                                                        \
                out[(size_t)((tb) + s_) * HBV_B + bA + ci * 512] = qr;         \
        }                                                                      \
    }                                                                          \
} while (0)

        float Pf[2][15], Tf[2][15], Ef[2][15];

        // p=0: snow c0 -> parity 0
        SNOWLOAD(0, 15); SNOW_RUN(15, lane); __syncthreads();
        // p=1: snow c1 -> parity 1
        SNOWLOAD(1, 15); SNOW_RUN(15, BUFSZ + lane); __syncthreads();
        // p=2..132: snow c=p (parity p&1); route c=p-2 (parity p&1)
#pragma unroll 1
        for (int p = 2; p <= 132; ++p) {
            const int po = (p & 1) * BUFSZ + lane;
            SNOWLOAD(p, 15);
            SNOW_RUN(15, po);
            ROUTE_RUN(15, po, 15 * (p - 2));
            __syncthreads();
        }
        // p=133: snow tail c133 (5, parity 1); route c131 (parity 1)
        SNOWLOAD(133, 5); SNOW_RUN(5, BUFSZ + lane);
        ROUTE_RUN(15, BUFSZ + lane, 1965); __syncthreads();
        // p=134: route c132 (parity 0)
        ROUTE_RUN(15, lane, 1980); __syncthreads();
        // p=135: route tail c133 (5, parity 1)
        ROUTE_RUN(5, BUFSZ + lane, 1995);
        // 135 barriers.
#undef SNOWLOAD
#undef SNOW_RUN
#undef ROUTE_RUN
    }
}

extern "C" void kernel_launch(void* const* d_in, const int* in_sizes, int n_in,
                              void* d_out, int out_size, void* d_ws, size_t ws_size,
                              hipStream_t stream) {
    const float* x_phy = (const float*)d_in[0];   // (2000,1024,3) fp32
    const float* ps    = (const float*)d_in[1];   // (1024,288)    fp32
    float* out         = (float*)d_out;           // (2000,1024)   fp32

    // 128 blocks x 128 threads; each soil lane advances 2 independent cells
    // so the ~250-cyc chain latency of one absorbs the other's issue.
    hbv_dual_kernel<<<128, 128, 0, stream>>>(x_phy, ps, out);
}

// Round 8
// 314.718 us; speedup vs baseline: 2.5716x; 2.5716x over previous
//
#include <hip/hip_runtime.h>

#define HBV_B  1024
#define HBV_NZ 1e-5f
#define BUFSZ  (15 * 64)       // one 15-step chunk buffer (64 lanes)

// ---------------------------------------------------------------------------
// SMT-overlap pipeline: 128 blocks x 512 threads (8 waves) -> 2 waves/SIMD.
// Roles (wv = tid>>6): set = wv>>2 (cells +0 / +512), role = wv&3:
//   role 0 (w0,w4): SOIL  — the critical SM/SUZ/SLZ recurrence (R5 math).
//   role 1 (w1,w5): ROUTE — 15-tap gamma FIR + 16-lane DPP mean + store.
//   role 2 (w2,w6): SNOW  — forcing loads + snow recurrence -> rt, log2PET.
//   role 3 (w3,w7): idler — barrier-matching only.
// Why: R4-R7 calibration shows per-step soil time = issue(~90) + K(~230,
// chain latency dominated by 4 chained v_log/v_exp @ ~55cyc). A single wave
// cannot fill its own chain stalls (in-order + compiler), but a co-resident
// wave on the same SIMD can (hw round-robin). With 8 waves/CU, every SIMD
// hosts 2 waves under either placement rule (i%4 or sequential fill), so
// soil stalls absorb the partner wave's issue -> pace ~max(issue_sum, K).
// Phase machine, 136 barriers/wave:
//   phase p: snow chunk p (p<=133) | soil chunk p-1 (1<=p<=134)
//            | route chunk p-2 (2<=p<=135).  Buffers parity = chunk&1.
// ---------------------------------------------------------------------------

struct F3 { float x, y, z; };

#define DPP_ADD_ROR(x, ctrl) do {                                              \
    int _r = __builtin_amdgcn_update_dpp(0, __float_as_int(x),                 \
                                         (ctrl), 0xF, 0xF, true);              \
    (x) += __int_as_float(_r);                                                 \
} while (0)

// ---- soil step: R5 math verbatim (absmax-proven) --------------------------
#define SOIL_STEP(s, rt_, lp_, qdst) do {                                      \
    float rt   = (rt_);                                                        \
    float lp   = (lp_);                                                        \
    float cpet = lp + nBEloglpfc;                                              \
    float CSLZ = parC * SLZ;                                                   \
    float c1   = __builtin_fmaf(-CSLZ, invFC, 1.0f);                           \
    float SMrt = SM + rt;                                                      \
    float lSM = __builtin_amdgcn_logf(SM);                                     \
    float esw = fminf(__builtin_fmaf(parBETA, lSM, nBlogFC), 0.0f);            \
    float sw  = __builtin_amdgcn_exp2f(esw);                                   \
    float SM1 = __builtin_fmaf(-rt, sw, SMrt);                                 \
    float SM2 = fminf(SM1, parFC);                                             \
    float SM3 = __builtin_fmaf(SM2, c1, CSLZ);                                 \
    float lS3 = __builtin_amdgcn_logf(SM3);                                    \
    float eef = fminf(__builtin_fmaf(parBETAET, lS3, cpet), lp);               \
    float PETef = __builtin_amdgcn_exp2f(eef);                                 \
    SM = fmaxf(SM3 - PETef, HBV_NZ);                                           \
    float U_ = __builtin_fmaf(rt, sw, SM1 - SM2);   /* recharge+excess */      \
    float S_ = SUZ + U_;                                                       \
    float P_ = fminf(S_, parPERC);                                             \
    float A_ = S_ - P_;                                                        \
    float B_ = fminf(A_, __builtin_fmaf(K0c, A_, K0UZL));                      \
    SUZ = K1c * B_;                                                            \
    float L_ = SLZ - (SM3 - SM2) + P_;                                         \
    SLZ = K2c * L_;                                                            \
    (qdst)[(s) * 64] = __builtin_fmaf(parK2, L_, A_ - SUZ);                    \
} while (0)

#define SOIL_CHUNK(n, po) do {                                                 \
    const float* rs = &rtS[set][(po)];                                         \
    const float* ls = &lpS[set][(po)];                                         \
    float* qd = &qS[set][(po)];                                                \
    float rr[15], lpv[15];                                                     \
    _Pragma("unroll")                                                          \
    for (int k_ = 0; k_ < (n); ++k_) {                                         \
        rr[k_]  = rs[k_ * 64];                                                 \
        lpv[k_] = ls[k_ * 64];                                                 \
    }                                                                          \
    _Pragma("unroll")                                                          \
    for (int s_ = 0; s_ < (n); ++s_) SOIL_STEP(s_, rr[s_], lpv[s_], qd);       \
} while (0)

// ---- snow: forcing load + forcing-only recurrence -> rt, log2(PET) --------
#define SNOW_PHASE(n, cidx) do {                                               \
    float Pf[15], Tf[15], Ef[15];                                              \
    _Pragma("unroll")                                                          \
    for (int k_ = 0; k_ < (n); ++k_) {                                         \
        F3 f = xb3[(size_t)((cidx) * 15 + k_) * HBV_B];                        \
        Pf[k_] = f.x; Tf[k_] = f.y; Ef[k_] = f.z;                              \
    }                                                                          \
    float* rd = &rtS[set][((cidx) & 1) * BUFSZ + lane];                        \
    float* ld = &lpS[set][((cidx) & 1) * BUFSZ + lane];                        \
    _Pragma("unroll")                                                          \
    for (int s_ = 0; s_ < (n); ++s_) {                                         \
        float Pm = Pf[s_], Tc = Tf[s_];                                        \
        float rain = (Tc >= parTT) ? Pm : 0.0f;                                \
        SNW += Pm - rain;                                                      \
        float melt = fminf(fmaxf(__builtin_fmaf(parCFMAX, Tc, negCT), 0.0f),   \
                           SNW);                                               \
        MLT += melt; SNW -= melt;                                              \
        float rfz = fminf(fmaxf(__builtin_fmaf(-CFRC, Tc, CFRCTT), 0.0f),      \
                          MLT);                                                \
        SNW += rfz; MLT -= rfz;                                                \
        float tosoil = fmaxf(__builtin_fmaf(-parCWH, SNW, MLT), 0.0f);         \
        MLT -= tosoil;                                                         \
        rd[s_ * 64] = rain + tosoil;                                           \
        ld[s_ * 64] = __builtin_amdgcn_logf(Ef[s_]);                           \
    }                                                                          \
} while (0)

// ---- route: LDS -> 15-tap FIR ring -> DPP mean over m -> global store -----
#define ROUTE_PHASE(n, cidx) do {                                              \
    const float* qsrc = &qS[set][((cidx) & 1) * BUFSZ + lane];                 \
    float qq[15];                                                              \
    _Pragma("unroll")                                                          \
    for (int k_ = 0; k_ < (n); ++k_) qq[k_] = qsrc[k_ * 64];                   \
    _Pragma("unroll")                                                          \
    for (int s_ = 0; s_ < (n); ++s_) {                                         \
        q[s_] = qq[s_];                                                        \
        float qr = 0.0f;                                                       \
        _Pragma("unroll")                                                      \
        for (int k_ = 0; k_ < 15; ++k_)                                        \
            qr += w[k_] * q[(s_ - k_ + 15) % 15];                              \
        DPP_ADD_ROR(qr, 0x128);                                                \
        DPP_ADD_ROR(qr, 0x124);                                                \
        DPP_ADD_ROR(qr, 0x122);                                                \
        DPP_ADD_ROR(qr, 0x121);                                                \
        if (m == 0) out[(size_t)((cidx) * 15 + s_) * HBV_B + b] = qr;          \
    }                                                                          \
} while (0)

__global__ __launch_bounds__(512, 1)
void hbv_smt_kernel(const float* __restrict__ x_phy,   // (2000, 1024, 3)
                    const float* __restrict__ ps,      // (1024, 288)
                    float* __restrict__ out)           // (2000, 1024)
{
    const int lane = (int)threadIdx.x & 63;
    const int wv   = (int)threadIdx.x >> 6;
    const int set  = wv >> 2;                 // 0: cells +0, 1: cells +512
    const int role = wv & 3;                  // 0 soil, 1 route, 2 snow, 3 idle
    const int b    = blockIdx.x * 4 + (lane >> 4) + set * 512;
    const int m    = lane & 15;

    __shared__ float rtS[2][2 * BUFSZ];   // snow -> soil : rain+tosoil
    __shared__ float lpS[2][2 * BUFSZ];   // snow -> soil : log2(PET)
    __shared__ float qS [2][2 * BUFSZ];   // soil -> route: Qsim

    const float* __restrict__ pb = ps + (size_t)b * 288;

    if (role == 0) {
        // --------------------------- SOIL ----------------------------------
        const float parBETA   = 1.0f   + pb[ 0*16 + m] * 5.0f;
        const float parFC     = 50.0f  + pb[ 1*16 + m] * 950.0f;
        const float parK0     = 0.05f  + pb[ 2*16 + m] * 0.85f;
        const float parK1     = 0.01f  + pb[ 3*16 + m] * 0.49f;
        const float parK2     = 0.001f + pb[ 4*16 + m] * 0.199f;
        const float parLP     = 0.2f   + pb[ 5*16 + m] * 0.8f;
        const float parPERC   =          pb[ 6*16 + m] * 10.0f;
        const float parUZL    =          pb[ 7*16 + m] * 100.0f;
        const float parBETAET = 0.3f   + pb[12*16 + m] * 4.7f;
        const float parC      =          pb[13*16 + m];
        const float invFC  = 1.0f / parFC;
        const float K0c    = 1.0f - parK0;
        const float K0UZL  = parK0 * parUZL;
        const float K1c    = 1.0f - parK1;
        const float K2c    = 1.0f - parK2;
        const float nBlogFC    = -parBETA   * __builtin_amdgcn_logf(parFC);
        const float nBEloglpfc = -parBETAET * __builtin_amdgcn_logf(parLP * parFC);

        float SM = HBV_NZ, SUZ = HBV_NZ, SLZ = HBV_NZ;

        __syncthreads();                                  // phase 0
#pragma unroll 1
        for (int c = 0; c < 133; ++c) {                   // phases 1..133
            SOIL_CHUNK(15, (c & 1) * BUFSZ + lane);
            __syncthreads();
        }
        SOIL_CHUNK(5, BUFSZ + lane);                      // chunk 133, ph 134
        __syncthreads();
        __syncthreads();                                  // phase 135
        // 136 barriers.
    } else if (role == 2) {
        // --------------------------- SNOW ----------------------------------
        const float parTT    = -2.5f + pb[ 8*16 + m] * 5.0f;
        const float parCFMAX = 0.5f  + pb[ 9*16 + m] * 9.5f;
        const float parCFR   =         pb[10*16 + m] * 0.1f;
        const float parCWH   =         pb[11*16 + m] * 0.2f;
        const float CFRC   = parCFR * parCFMAX;
        const float negCT  = -parCFMAX * parTT;
        const float CFRCTT =  CFRC * parTT;
        float SNW = HBV_NZ, MLT = HBV_NZ;
        const F3* __restrict__ xb3 = (const F3*)x_phy + b;

#pragma unroll 1
        for (int p = 0; p < 133; ++p) {                   // phases 0..132
            SNOW_PHASE(15, p);
            __syncthreads();
        }
        SNOW_PHASE(5, 133);                               // phase 133
        __syncthreads();
        __syncthreads();                                  // phase 134
        __syncthreads();                                  // phase 135
        // 136 barriers.
    } else if (role == 1) {
        // --------------------------- ROUTE ---------------------------------
        const float rout_a = pb[256 + m]      * 2.9f;
        const float rout_b = pb[256 + 16 + m] * 6.5f;
        // w[k] ∝ t_k^(a-1) exp(-t_k/theta); Gamma/theta^a cancels under
        // normalization; pre-scaled by 1/16 for the mean over m.
        const float aa    = fmaxf(rout_a, 0.0f) + 0.1f;
        const float theta = fmaxf(rout_b, 0.0f) + 0.5f;
        const float am1   = aa - 1.0f;
        const float nit   = -1.4426950408889634f / theta;
        float w[15];
        float wsum = 0.0f;
#pragma unroll
        for (int k = 0; k < 15; ++k) {
            float tk = (float)k + 0.5f;
            float e  = am1 * __builtin_amdgcn_logf(tk) + nit * tk;
            w[k] = __builtin_amdgcn_exp2f(e);
            wsum += w[k];
        }
        const float wscale = 1.0f / (16.0f * wsum);
#pragma unroll
        for (int k = 0; k < 15; ++k) w[k] *= wscale;
        float q[15];
#pragma unroll
        for (int k = 0; k < 15; ++k) q[k] = 0.0f;

        __syncthreads();                                  // phase 0
        __syncthreads();                                  // phase 1
#pragma unroll 1
        for (int c = 0; c < 133; ++c) {                   // phases 2..134
            ROUTE_PHASE(15, c);
            __syncthreads();
        }
        ROUTE_PHASE(5, 133);                              // phase 135
        __syncthreads();
        // 136 barriers.
    } else {
        // --------------------------- IDLER ---------------------------------
#pragma unroll 1
        for (int p = 0; p < 136; ++p) __syncthreads();
    }
}

extern "C" void kernel_launch(void* const* d_in, const int* in_sizes, int n_in,
                              void* d_out, int out_size, void* d_ws, size_t ws_size,
                              hipStream_t stream) {
    const float* x_phy = (const float*)d_in[0];   // (2000,1024,3) fp32
    const float* ps    = (const float*)d_in[1];   // (1024,288)    fp32
    float* out         = (float*)d_out;           // (2000,1024)   fp32

    // 128 blocks x 512 threads (8 waves) -> 2 waves per SIMD: co-resident
    // waves' issue fills the soil chain's transcendental-latency stalls.
    hbv_smt_kernel<<<128, 512, 0, stream>>>(x_phy, ps, out);
}